// Round 9
// baseline (331.578 us; speedup 1.0000x reference)
//
#include <hip/hip_runtime.h>
#include <math.h>

// Problem constants
#define BB 512
#define TT 2048
#define AA 16
#define NTOT (512LL * 2048LL * 16LL)   // 16,777,216
#define GAMMA 0.99f
#define GLAM  0.9405f                  // gamma * lam, matches python double->f32
#define ENTC  1.4189385332046727f      // 0.5 + 0.5*log(2*pi)

#define QPB 4                          // blocks per batch row (phase-2 split)
#define NB1 (BB * QPB)                 // 2048 blocks for fused kernel
#define NB3 2048                       // blocks for out RMW kernel

typedef float f32x4 __attribute__((ext_vector_type(4)));

// Volatile-asm 16B global loads (proven r5: ordering and liveness immune to
// the source-pipeline collapse seen in r1/r2/r4).
#define NT_LOAD(dst, off, base) \
    asm volatile("global_load_dwordx4 %0, %1, %2 nt" \
                 : "=v"(dst) : "v"(off), "s"(base))
#define C_LOAD(dst, off, base) \
    asm volatile("global_load_dwordx4 %0, %1, %2" \
                 : "=v"(dst) : "v"(off), "s"(base))
#define VM_WAIT_FENCE(n) do { \
    asm volatile("s_waitcnt vmcnt(" #n ")"); \
    __builtin_amdgcn_sched_barrier(0); } while (0)

// ---------------------------------------------------------------------------
__device__ __forceinline__ float obj1(float x, float m, float s,
                                      float om, float os, float ad)
{
    float rs  = __builtin_amdgcn_rcpf(s);
    float ros = __builtin_amdgcn_rcpf(os);
    float z   = (x - m) * rs;
    float zo  = (x - om) * ros;
    float d   = 0.5f * (zo * zo - z * z);
    float ratio = os * rs * __expf(d);
    return fminf(ad * ratio, ad * 0.8f);     // clipped == 0.8 (faithful clip bug)
}

__device__ __forceinline__ double obj4d(f32x4 m, f32x4 s, f32x4 om, f32x4 os,
                                        f32x4 x, float ad)
{
    float o0 = obj1(x.x, m.x, s.x, om.x, os.x, ad);
    float o1 = obj1(x.y, m.y, s.y, om.y, os.y, ad);
    float o2 = obj1(x.z, m.z, s.z, om.z, os.z, ad);
    float o3 = obj1(x.w, m.w, s.w, om.w, os.w, ad);
    return (double)o0 + (double)o1 + (double)o2 + (double)o3;
}

// ---------------------------------------------------------------------------
// K1: FUSED GAE + PPO objective + ENTROPY WRITE. r8 body (85us, natural
// blockIdx, 20-deep asm pipeline, relaxed atomic) + one addition: sigma is
// already in registers, so after each cluster's obj4d the dead sigma regs
// are overwritten in place with log(sigma) and stored to out at the end.
// K2 then only does out[i] += (mean+ENTC) on freshly-L3-resident data
// instead of re-reading 85us-cold sigma. Slack test: K1 has no saturated
// resource (HBM 36%, VALU 14%), so the +64MB write should be ~free.
// ---------------------------------------------------------------------------
__global__ __launch_bounds__(512) void gae_obj_kernel(
    const float* __restrict__ rewards, const float* __restrict__ vout,
    const int* __restrict__ dones,
    const float* __restrict__ mu, const float* __restrict__ sigma,
    const float* __restrict__ old_mu, const float* __restrict__ old_sigma,
    const float* __restrict__ actions,
    float* __restrict__ out, double* __restrict__ total)
{
    __shared__ float  adv_s[TT];          // 8 KB
    __shared__ float  wA[8], wB[8];
    __shared__ double wsum[8];

    const int b    = blockIdx.x >> 2;     // batch row (natural order)
    const int q    = blockIdx.x & 3;      // quarter of the row
    const int tid  = threadIdx.x;
    const int lane = tid & 63;
    const int wave = tid >> 6;

    // ---------------- Phase 1: full-row GAE scan into LDS ----------------
    {
        const float* rw = rewards + (size_t)b * TT;
        const float* V  = vout    + (size_t)b * (TT + 1);
        const int*   dn = dones   + (size_t)b * TT;

        const int t_lo = TT - 4 - 4 * tid;          // multiple of 4, >= 0

        f32x4 r4 = *(const f32x4*)(rw + t_lo);
        int4  d4 = *(const int4*)(dn + t_lo);
        int   dt = (tid == 0) ? 1 : dn[t_lo + 4];   // dn[2048] OOB for tid 0; unused there
        float vv[5];
        #pragma unroll
        for (int j = 0; j < 5; ++j) vv[j] = V[t_lo + j];  // V[2048] valid (T+1 cols)

        float rr[4] = {r4.x, r4.y, r4.z, r4.w};
        int   dd[5] = {d4.x, d4.y, d4.z, d4.w, dt};

        float ak[4], bk[4];
        float SA = 1.f, SB = 0.f;                   // segment composite (earliest-first)
        #pragma unroll
        for (int k = 0; k < 4; ++k) {
            // u = tid*4 + k ; t = TT-1-u = t_lo + (3-k)
            const int j = 3 - k;
            float bu = rr[j] + GAMMA * vv[j + 1] - vv[j];
            float au = GLAM * (1.f - (float)dd[j + 1]);
            if (k == 0 && tid == 0) { au = 0.f; bu = 0.f; }   // u == 0
            ak[k] = au; bk[k] = bu;
            SB = au * SB + bu;
            SA = au * SA;
        }

        #pragma unroll
        for (int off = 1; off < 64; off <<= 1) {
            float pA = __shfl_up(SA, off, 64);
            float pB = __shfl_up(SB, off, 64);
            if (lane >= off) { SB = SA * pB + SB; SA = SA * pA; }
        }

        if (lane == 63) { wA[wave] = SA; wB[wave] = SB; }
        __syncthreads();

        float PA = 1.f, PB = 0.f;
        for (int w = 0; w < wave; ++w) {
            float aw = wA[w], bw = wB[w];
            PB = aw * PB + bw;
            PA = aw * PA;
        }

        float EA = __shfl_up(SA, 1, 64);
        float EB = __shfl_up(SB, 1, 64);
        if (lane == 0) { EA = 1.f; EB = 0.f; }

        float x = EA * PB + EB;
        float outb[4];
        #pragma unroll
        for (int k = 0; k < 4; ++k) {
            x = ak[k] * x + bk[k];
            outb[3 - k] = x;                        // t = t_lo + (3-k)
        }
        *(f32x4*)(adv_s + t_lo) = (f32x4){outb[0], outb[1], outb[2], outb[3]};
    }
    __syncthreads();

    // ---------------- Phase 2: objective over this block's quarter --------
    const size_t basef4 = (size_t)b * 8192 + (size_t)q * 2048;
    const f32x4* m4  = (const f32x4*)mu        + basef4;
    const f32x4* s4  = (const f32x4*)sigma     + basef4;
    const f32x4* om4 = (const f32x4*)old_mu    + basef4;
    const f32x4* os4 = (const f32x4*)old_sigma + basef4;
    const f32x4* x4  = (const f32x4*)actions   + basef4;
    f32x4*       ou4 = (f32x4*)out             + basef4;
    const float* advq = adv_s + q * 512;

    const int ai = tid >> 2;
    const float Aa = advq[ai];
    const float Ba = advq[ai + 128];
    const float Ca = advq[ai + 256];
    const float Da = advq[ai + 384];

    const uint32_t o0 = (uint32_t)tid * 16u;
    const uint32_t o1 = o0 + 512u * 16u;
    const uint32_t o2 = o0 + 1024u * 16u;
    const uint32_t o3 = o0 + 1536u * 16u;

    f32x4 Am, As, Aom, Aos, Ax;
    f32x4 Bm, Bs, Bom, Bos, Bx;
    f32x4 Cm, Cs, Com, Cos, Cx;
    f32x4 Dm, Ds, Dom, Dos, Dx;

    // 20 loads in flight per thread; ALL streams NT now (sigma's cached
    // policy existed only for K2's old re-read; L3 residency now reserved
    // for the out buffer K2 re-reads).
    NT_LOAD(Am, o0, m4);  NT_LOAD(As, o0, s4);  NT_LOAD(Aom, o0, om4);
    NT_LOAD(Aos, o0, os4);  NT_LOAD(Ax, o0, x4);
    NT_LOAD(Bm, o1, m4);  NT_LOAD(Bs, o1, s4);  NT_LOAD(Bom, o1, om4);
    NT_LOAD(Bos, o1, os4);  NT_LOAD(Bx, o1, x4);
    NT_LOAD(Cm, o2, m4);  NT_LOAD(Cs, o2, s4);  NT_LOAD(Com, o2, om4);
    NT_LOAD(Cos, o2, os4);  NT_LOAD(Cx, o2, x4);
    NT_LOAD(Dm, o3, m4);  NT_LOAD(Ds, o3, s4);  NT_LOAD(Dom, o3, om4);
    NT_LOAD(Dos, o3, os4);  NT_LOAD(Dx, o3, x4);

    VM_WAIT_FENCE(15);
    double lsum = obj4d(Am, As, Aom, Aos, Ax, Aa);
    As.x = __logf(As.x); As.y = __logf(As.y);    // sigma regs dead -> log(sigma)
    As.z = __logf(As.z); As.w = __logf(As.w);
    VM_WAIT_FENCE(10);
    lsum += obj4d(Bm, Bs, Bom, Bos, Bx, Ba);
    Bs.x = __logf(Bs.x); Bs.y = __logf(Bs.y);
    Bs.z = __logf(Bs.z); Bs.w = __logf(Bs.w);
    VM_WAIT_FENCE(5);
    lsum += obj4d(Cm, Cs, Com, Cos, Cx, Ca);
    Cs.x = __logf(Cs.x); Cs.y = __logf(Cs.y);
    Cs.z = __logf(Cs.z); Cs.w = __logf(Cs.w);
    VM_WAIT_FENCE(0);
    lsum += obj4d(Dm, Ds, Dom, Dos, Dx, Da);
    Ds.x = __logf(Ds.x); Ds.y = __logf(Ds.y);
    Ds.z = __logf(Ds.z); Ds.w = __logf(Ds.w);

    // log(sigma) -> out (plain stores: dirty L2 writes back to memory-side
    // L3 at dispatch end, so K2's RMW reads are L3-hits). K2 adds mean+ENTC.
    ou4[tid]          = As;
    ou4[tid + 512u]   = Bs;
    ou4[tid + 1024u]  = Cs;
    ou4[tid + 1536u]  = Ds;

    // block reduce (8 waves)
    #pragma unroll
    for (int off = 32; off > 0; off >>= 1)
        lsum += __shfl_down(lsum, off, 64);
    if (lane == 0) wsum[wave] = lsum;
    __syncthreads();
    if (tid == 0) {
        double t = 0.0;
        #pragma unroll
        for (int w = 0; w < 8; ++w) t += wsum[w];
        // RELAXED device atomic: no fences, no cache writeback (r6 lesson:
        // per-block ACQ_REL release = L2 writeback storm, 2.3x regression).
        __hip_atomic_fetch_add(total, t, __ATOMIC_RELAXED,
                               __HIP_MEMORY_SCOPE_AGENT);
    }
}

// ---------------------------------------------------------------------------
// K2: out[i] = (mean + ENTC) + out[i]   (out holds log(sigma) from K1).
// FP-identical association to the previous mc + logf(s). Reads are
// L3-warm (written <100us ago, flushed at dispatch boundary). 8 asm loads
// in flight, one drain, NT stores (out never read again on device).
// ---------------------------------------------------------------------------
__global__ __launch_bounds__(256) void out_kernel(
    const double* __restrict__ total, float* __restrict__ out)
{
    const int tid = threadIdx.x;
    const uint32_t Q = (uint32_t)(NTOT / 4 / 8);        // 524,288 f32x4/stream
    const uint32_t v = (uint32_t)blockIdx.x * 256u + (uint32_t)tid;  // < Q
    f32x4* o4 = (f32x4*)out;

    const double tot = *total;                   // uniform s_load

    f32x4 a0, a1, a2, a3, a4, a5, a6, a7;
    C_LOAD(a0, (v + 0u * Q) * 16u, o4);
    C_LOAD(a1, (v + 1u * Q) * 16u, o4);
    C_LOAD(a2, (v + 2u * Q) * 16u, o4);
    C_LOAD(a3, (v + 3u * Q) * 16u, o4);
    C_LOAD(a4, (v + 4u * Q) * 16u, o4);
    C_LOAD(a5, (v + 5u * Q) * 16u, o4);
    C_LOAD(a6, (v + 6u * Q) * 16u, o4);
    C_LOAD(a7, (v + 7u * Q) * 16u, o4);

    const float mc = (float)(tot / (double)NTOT) + ENTC;   // mean + ENTC

    VM_WAIT_FENCE(0);                            // all 8 streams landed

    a0.x = mc + a0.x; a0.y = mc + a0.y; a0.z = mc + a0.z; a0.w = mc + a0.w;
    a1.x = mc + a1.x; a1.y = mc + a1.y; a1.z = mc + a1.z; a1.w = mc + a1.w;
    a2.x = mc + a2.x; a2.y = mc + a2.y; a2.z = mc + a2.z; a2.w = mc + a2.w;
    a3.x = mc + a3.x; a3.y = mc + a3.y; a3.z = mc + a3.z; a3.w = mc + a3.w;
    a4.x = mc + a4.x; a4.y = mc + a4.y; a4.z = mc + a4.z; a4.w = mc + a4.w;
    a5.x = mc + a5.x; a5.y = mc + a5.y; a5.z = mc + a5.z; a5.w = mc + a5.w;
    a6.x = mc + a6.x; a6.y = mc + a6.y; a6.z = mc + a6.z; a6.w = mc + a6.w;
    a7.x = mc + a7.x; a7.y = mc + a7.y; a7.z = mc + a7.z; a7.w = mc + a7.w;

    __builtin_nontemporal_store(a0, o4 + v + 0u * Q);
    __builtin_nontemporal_store(a1, o4 + v + 1u * Q);
    __builtin_nontemporal_store(a2, o4 + v + 2u * Q);
    __builtin_nontemporal_store(a3, o4 + v + 3u * Q);
    __builtin_nontemporal_store(a4, o4 + v + 4u * Q);
    __builtin_nontemporal_store(a5, o4 + v + 5u * Q);
    __builtin_nontemporal_store(a6, o4 + v + 6u * Q);
    __builtin_nontemporal_store(a7, o4 + v + 7u * Q);
}

// ---------------------------------------------------------------------------
extern "C" void kernel_launch(void* const* d_in, const int* in_sizes, int n_in,
                              void* d_out, int out_size, void* d_ws, size_t ws_size,
                              hipStream_t stream) {
    const float* rewards   = (const float*)d_in[0];   // [B,T]
    const float* critic    = (const float*)d_in[1];   // [B,T+1]
    const float* mu        = (const float*)d_in[2];   // [B,T,A]
    const float* sigma     = (const float*)d_in[3];
    const float* old_mu    = (const float*)d_in[4];
    const float* old_sigma = (const float*)d_in[5];
    const float* actions   = (const float*)d_in[6];
    const int*   dones     = (const int*)d_in[7];     // [B,T]
    float* out = (float*)d_out;

    double* total = (double*)d_ws;                    // 8 B accumulator

    hipMemsetAsync(total, 0, sizeof(double), stream);
    gae_obj_kernel<<<NB1, 512, 0, stream>>>(rewards, critic, dones,
                                            mu, sigma, old_mu, old_sigma,
                                            actions, out, total);
    out_kernel<<<NB3, 256, 0, stream>>>(total, out);
}